// Round 1
// baseline (502.174 us; speedup 1.0000x reference)
//
#include <hip/hip_runtime.h>

#define BATCH   65536
#define T       792
#define ND      99
#define NL      16
#define NJ      198   // float4 chunks per row (792/4); row stride 3168 B is 16B-aligned

__global__ void llb_zero_ws(float* ws) { ws[0] = 0.0f; }

__global__ __launch_bounds__(256) void llb_main(
    const float* __restrict__ pred,   // [BATCH, 792]
    const float* __restrict__ dem,    // [BATCH, 99]
    const int*   __restrict__ t2l,    // [792]
    const float* __restrict__ cap,    // [16]
    float* __restrict__ ws)
{
    __shared__ float bins[4][NL];     // per-wave bins, no cross-wave races
    const int lane  = threadIdx.x & 63;
    const int wid   = threadIdx.x >> 6;
    const int gwave = (int)((blockIdx.x * blockDim.x + threadIdx.x) >> 6);
    const int nwave = (int)((gridDim.x * blockDim.x) >> 6);

    // Row-invariant: preload this lane's 4 link-quads into registers (16 VGPRs)
    int4 lk[4];
#pragma unroll
    for (int k = 0; k < 4; ++k) {
        int j = 64 * k + lane;
        if (j > NJ - 1) j = NJ - 1;           // clamp (lanes >=6 at k=3 are masked later)
        lk[k] = ((const int4*)t2l)[j];
    }
    float invcap = 0.0f;
    if (lane < NL) invcap = 1.0f / (cap[lane] + 1e-8f);

    float acc = 0.0f;
    for (int row = gwave; row < BATCH; row += nwave) {
        if (lane < NL) bins[wid][lane] = 0.0f;   // in-order DS per wave; no barrier needed

        const float4* prow = (const float4*)(pred + (size_t)row * T);
        const float*  drow = dem + (size_t)row * ND;

#pragma unroll
        for (int k = 0; k < 4; ++k) {
            const int j = 64 * k + lane;
            if (k < 3 || lane < 6) {              // k<3 folds away under unroll
                float4 p = prow[j];               // 1 KiB coalesced wave load
                float  d = drow[j >> 1];          // aligned 4-run sits in one dest-group of 8
                atomicAdd(&bins[wid][lk[k].x], p.x * d);
                atomicAdd(&bins[wid][lk[k].y], p.y * d);
                atomicAdd(&bins[wid][lk[k].z], p.z * d);
                atomicAdd(&bins[wid][lk[k].w], p.w * d);
            }
        }

        float u = 0.0f;
        if (lane < NL) u = bins[wid][lane] * invcap;
        // width-16 butterfly over lanes 0..15: sum, sum of squares, max
        float s = u, q = u * u, m = u;
#pragma unroll
        for (int off = 8; off >= 1; off >>= 1) {
            s += __shfl_xor(s, off, 16);
            q += __shfl_xor(q, off, 16);
            float om = __shfl_xor(m, off, 16);
            m = m > om ? m : om;
        }
        if (lane == 0) {
            float var = (q - s * s * (1.0f / 16.0f)) * (1.0f / 15.0f);  // ddof=1
            acc += var + 0.5f * m;
        }
    }
    if (lane == 0) atomicAdd(ws, acc);
}

__global__ void llb_final(const float* __restrict__ ws, float* __restrict__ out) {
    out[0] = ws[0] * (1.0f / (float)BATCH);
}

extern "C" void kernel_launch(void* const* d_in, const int* in_sizes, int n_in,
                              void* d_out, int out_size, void* d_ws, size_t ws_size,
                              hipStream_t stream) {
    const float* pred = (const float*)d_in[0];
    const float* dem  = (const float*)d_in[1];
    const int*   t2l  = (const int*)d_in[2];
    const float* cap  = (const float*)d_in[3];
    float* out = (float*)d_out;
    float* ws  = (float*)d_ws;

    llb_zero_ws<<<1, 1, 0, stream>>>(ws);
    // 2048 blocks x 256 thr = 8192 waves = 8 waves/SIMD; 8 rows per wave
    llb_main<<<2048, 256, 0, stream>>>(pred, dem, t2l, cap, ws);
    llb_final<<<1, 1, 0, stream>>>(ws, out);
}

// Round 2
// 324.108 us; speedup vs baseline: 1.5494x; 1.5494x over previous
//
#include <hip/hip_runtime.h>

#define T      792
#define ND     99
#define NL     16
#define KBLK   25        // 25 k-blocks of 32 (K padded 792 -> 800)
#define BATCH  65536
#define NTILES (BATCH / 16)   // 4096 tiles of 16 batch rows

typedef __attribute__((ext_vector_type(8))) short  short8;   // 8 bf16 in 4 VGPRs
typedef __attribute__((ext_vector_type(4))) float  float4v;

// f32 -> bf16 round-to-nearest-even (avoid __hip_bfloat16 ABI differences)
__device__ inline unsigned short f2bf(float x) {
    union { float f; unsigned u; } c; c.f = x;
    unsigned r = (c.u + 0x7FFFu + ((c.u >> 16) & 1u)) >> 16;
    return (unsigned short)r;
}

__global__ __launch_bounds__(256) void llb_mfma(
    const float* __restrict__ pred,   // [BATCH, 792]
    const float* __restrict__ dem,    // [BATCH, 99]
    const int*   __restrict__ t2l,    // [792]
    const float* __restrict__ cap,    // [16]
    float* __restrict__ partial)      // [NTILES] per-wave loss partials
{
    // One-hot B fragments, row-invariant: B[k][n] = (t2l[k]==n) in bf16.
    // Layout matches A's k-map exactly, so any k-permutation error cancels.
    __shared__ short8 Bfrag[KBLK][64];           // 25 * 64 * 16B = 25,600 B

    const int lane = threadIdx.x & 63;
    const int wid  = threadIdx.x >> 6;
    const int g    = lane >> 4;                  // k-group 0..3
    const int n    = lane & 15;                  // col (link) / A-row-in-tile

    // Cooperative one-hot build: wave w handles kb = w, w+4, ...
    for (int kb = wid; kb < KBLK; kb += 4) {
        const int k0 = kb * 32 + g * 8;
        union { unsigned short us[8]; short8 v; } b;
#pragma unroll
        for (int j = 0; j < 8; ++j) {
            const int k = k0 + j;
            const int link = (k < T) ? t2l[k] : -1;   // pad k>=792 -> all-zero B
            b.us[j] = (link == n) ? (unsigned short)0x3F80 : (unsigned short)0;
        }
        Bfrag[kb][lane] = b.v;
    }
    __syncthreads();

    const float invcap = 1.0f / (cap[n] + 1e-8f);

    const int tile = (int)blockIdx.x * 4 + wid;  // 1024 blocks * 4 waves = 4096 tiles
    const int arow_i = tile * 16 + n;            // A fragment: m = lane&15
    const float* __restrict__ arow = pred + (size_t)arow_i * T;
    const float* __restrict__ drow = dem  + (size_t)arow_i * ND;

    float4v acc = {0.f, 0.f, 0.f, 0.f};
#pragma unroll 5
    for (int kb = 0; kb < KBLK; ++kb) {
        const int k0 = kb * 32 + g * 8;
        const int kc = (k0 <= T - 8) ? k0 : (T - 8);   // clamp pad group (B=0 there)
        int d0 = k0 >> 3;                               // dest of all 8 k's (aligned run)
        if (d0 > ND - 1) d0 = ND - 1;

        const float4v a0 = *(const float4v*)(arow + kc);
        const float4v a1 = *(const float4v*)(arow + kc + 4);
        const float   d  = drow[d0];

        union { unsigned short us[8]; short8 v; } af;
        af.us[0] = f2bf(a0.x * d); af.us[1] = f2bf(a0.y * d);
        af.us[2] = f2bf(a0.z * d); af.us[3] = f2bf(a0.w * d);
        af.us[4] = f2bf(a1.x * d); af.us[5] = f2bf(a1.y * d);
        af.us[6] = f2bf(a1.z * d); af.us[7] = f2bf(a1.w * d);

        acc = __builtin_amdgcn_mfma_f32_16x16x32_bf16(af.v, Bfrag[kb][lane], acc, 0, 0, 0);
    }

    // C/D layout (HW-verified): col = lane&15 (= link), row = (lane>>4)*4 + reg.
    float lsum = 0.f;
#pragma unroll
    for (int r = 0; r < 4; ++r) {
        const float u = acc[r] * invcap;
        float s = u, q = u * u, m = u;
#pragma unroll
        for (int off = 8; off >= 1; off >>= 1) {
            s += __shfl_xor(s, off, 16);
            q += __shfl_xor(q, off, 16);
            const float om = __shfl_xor(m, off, 16);
            m = m > om ? m : om;
        }
        if (n == 0) {
            const float var = (q - s * s * (1.0f / 16.0f)) * (1.0f / 15.0f);  // ddof=1
            lsum += var + 0.5f * m;
        }
    }
    // Combine the 4 group leaders (lanes 0,16,32,48); others hold 0.
    lsum += __shfl_xor(lsum, 16, 64);
    lsum += __shfl_xor(lsum, 32, 64);
    if (lane == 0) partial[tile] = lsum;   // distinct slots: no atomic contention
}

__global__ __launch_bounds__(256) void llb_reduce(
    const float* __restrict__ partial, float* __restrict__ out)
{
    float s = 0.f;
    for (int i = threadIdx.x; i < NTILES; i += 256) s += partial[i];
#pragma unroll
    for (int off = 32; off >= 1; off >>= 1) s += __shfl_xor(s, off, 64);
    __shared__ float red[4];
    if ((threadIdx.x & 63) == 0) red[threadIdx.x >> 6] = s;
    __syncthreads();
    if (threadIdx.x == 0)
        out[0] = (red[0] + red[1] + red[2] + red[3]) * (1.0f / (float)BATCH);
}

extern "C" void kernel_launch(void* const* d_in, const int* in_sizes, int n_in,
                              void* d_out, int out_size, void* d_ws, size_t ws_size,
                              hipStream_t stream) {
    const float* pred = (const float*)d_in[0];
    const float* dem  = (const float*)d_in[1];
    const int*   t2l  = (const int*)d_in[2];
    const float* cap  = (const float*)d_in[3];
    float* out     = (float*)d_out;
    float* partial = (float*)d_ws;            // 4096 floats = 16 KB scratch

    llb_mfma<<<NTILES / 4, 256, 0, stream>>>(pred, dem, t2l, cap, partial);
    llb_reduce<<<1, 256, 0, stream>>>(partial, out);
}

// Round 3
// 319.432 us; speedup vs baseline: 1.5721x; 1.0146x over previous
//
#include <hip/hip_runtime.h>

#define T      792
#define ND     99
#define NL     16
#define KBLK   25        // 25 k-blocks of 32 (K padded 792 -> 800)
#define BATCH  65536
#define NTILES (BATCH / 16)   // 4096 tiles of 16 batch rows

typedef __attribute__((ext_vector_type(8))) short  short8;   // 8 bf16 in 4 VGPRs
typedef __attribute__((ext_vector_type(4))) float  float4v;

// f32 -> bf16 round-to-nearest-even
__device__ inline unsigned short f2bf(float x) {
    union { float f; unsigned u; } c; c.f = x;
    return (unsigned short)((c.u + 0x7FFFu + ((c.u >> 16) & 1u)) >> 16);
}

// Wave pairs split K: even wave kb 0..12, odd wave kb 13..24; combine via LDS.
// B one-hot fragments are built on the fly from nibble-packed t2l (16 links = 4 bits),
// eliminating the 25.6 KB LDS B-table -> 32 waves/CU occupancy.
__global__ __launch_bounds__(256) void llb_mfma(
    const float* __restrict__ pred,   // [BATCH, 792]
    const float* __restrict__ dem,    // [BATCH, 99]
    const int*   __restrict__ t2l,    // [792]
    const float* __restrict__ cap,    // [16]
    float* __restrict__ partial)      // [NTILES]
{
    __shared__ unsigned packed[KBLK * 4];   // 100 words; word w = links of k=8w..8w+7
    __shared__ float4v  comb[2][64];        // odd-wave accumulator handoff

    const int lane = threadIdx.x & 63;
    const int wid  = threadIdx.x >> 6;
    const int g    = lane >> 4;             // k-group 0..3
    const int n    = lane & 15;             // col (link) / A-row-in-tile

    if (threadIdx.x < KBLK * 4) {
        const int w = threadIdx.x;
        unsigned u = 0;
#pragma unroll
        for (int j = 0; j < 8; ++j) {
            const int k = w * 8 + j;
            const unsigned link = (k < T) ? (unsigned)t2l[k] : 0u;  // pad value unused (d=0)
            u |= link << (4 * j);
        }
        packed[w] = u;
    }
    __syncthreads();

    const int tile   = (int)blockIdx.x * 2 + (wid >> 1);  // 2048 blocks * 2 tiles
    const int kb0    = (wid & 1) ? 13 : 0;
    const int kb1    = (wid & 1) ? KBLK : 13;
    const int arow_i = tile * 16 + n;                     // A fragment: m = lane&15
    const float* __restrict__ arow = pred + (size_t)arow_i * T;
    const float* __restrict__ drow = dem  + (size_t)arow_i * ND;

    float4v acc = {0.f, 0.f, 0.f, 0.f};
#pragma unroll 4
    for (int kb = kb0; kb < kb1; ++kb) {
        const int idx = kb * 4 + g;                  // packed-word index == demand index
        const int k0  = idx * 8;
        const int kc  = (k0 <= T - 8) ? k0 : (T - 8);   // keep pad-group load in bounds
        const float4v a0 = *(const float4v*)(arow + kc);
        const float4v a1 = *(const float4v*)(arow + kc + 4);
        const float   d  = (idx < ND) ? drow[idx] : 0.f;  // pad group contributes 0
        const unsigned u = packed[idx];              // broadcast within 16-lane group

        union { unsigned short us[8]; short8 v; } af, bf;
        af.us[0] = f2bf(a0.x * d); af.us[1] = f2bf(a0.y * d);
        af.us[2] = f2bf(a0.z * d); af.us[3] = f2bf(a0.w * d);
        af.us[4] = f2bf(a1.x * d); af.us[5] = f2bf(a1.y * d);
        af.us[6] = f2bf(a1.z * d); af.us[7] = f2bf(a1.w * d);
#pragma unroll
        for (int j = 0; j < 8; ++j)
            bf.us[j] = (((u >> (4 * j)) & 15u) == (unsigned)n)
                           ? (unsigned short)0x3F80 : (unsigned short)0;

        acc = __builtin_amdgcn_mfma_f32_16x16x32_bf16(af.v, bf.v, acc, 0, 0, 0);
    }

    // Combine K-split halves: odd wave hands its acc to its even partner.
    if (wid & 1) comb[wid >> 1][lane] = acc;
    __syncthreads();
    if (!(wid & 1)) {
        const float4v o = comb[wid >> 1][lane];
        const float invcap = 1.0f / (cap[n] + 1e-8f);
        // C/D layout (HW-verified): col = lane&15 (= link), row = (lane>>4)*4 + reg.
        float lsum = 0.f;
#pragma unroll
        for (int r = 0; r < 4; ++r) {
            const float uu = (acc[r] + o[r]) * invcap;
            float s = uu, q = uu * uu, m = uu;
#pragma unroll
            for (int off = 8; off >= 1; off >>= 1) {
                s += __shfl_xor(s, off, 16);
                q += __shfl_xor(q, off, 16);
                const float om = __shfl_xor(m, off, 16);
                m = m > om ? m : om;
            }
            if (n == 0) {
                const float var = (q - s * s * (1.0f / 16.0f)) * (1.0f / 15.0f);  // ddof=1
                lsum += var + 0.5f * m;
            }
        }
        lsum += __shfl_xor(lsum, 16, 64);   // fold the 4 group leaders
        lsum += __shfl_xor(lsum, 32, 64);
        if (lane == 0) partial[tile] = lsum;
    }
}

__global__ __launch_bounds__(256) void llb_reduce(
    const float* __restrict__ partial, float* __restrict__ out)
{
    float s = 0.f;
    for (int i = threadIdx.x; i < NTILES; i += 256) s += partial[i];
#pragma unroll
    for (int off = 32; off >= 1; off >>= 1) s += __shfl_xor(s, off, 64);
    __shared__ float red[4];
    if ((threadIdx.x & 63) == 0) red[threadIdx.x >> 6] = s;
    __syncthreads();
    if (threadIdx.x == 0)
        out[0] = (red[0] + red[1] + red[2] + red[3]) * (1.0f / (float)BATCH);
}

extern "C" void kernel_launch(void* const* d_in, const int* in_sizes, int n_in,
                              void* d_out, int out_size, void* d_ws, size_t ws_size,
                              hipStream_t stream) {
    const float* pred = (const float*)d_in[0];
    const float* dem  = (const float*)d_in[1];
    const int*   t2l  = (const int*)d_in[2];
    const float* cap  = (const float*)d_in[3];
    float* out     = (float*)d_out;
    float* partial = (float*)d_ws;            // 4096 floats = 16 KB scratch

    llb_mfma<<<NTILES / 2, 256, 0, stream>>>(pred, dem, t2l, cap, partial);
    llb_reduce<<<1, 256, 0, stream>>>(partial, out);
}